// Round 11
// baseline (124.134 us; speedup 1.0000x reference)
//
#include <hip/hip_runtime.h>

#define NB 8          // 7 full blocks + 1 partial block
#define DDIM 2048
#define THREADS 512   // one (b,t) row per block; PER=4 floats/thread
#define NWAVES (THREADS / 64)

typedef float f32x4 __attribute__((ext_vector_type(4)));

// 64-lane f32 add-reduction via DPP (VALU pipe, no DS ops). Total in lane 63.
__device__ __forceinline__ float wave_sum64(float x) {
    int t;
    t = __builtin_amdgcn_update_dpp(0, __float_as_int(x), 0x111, 0xf, 0xf, false); // row_shr:1
    x += __int_as_float(t);
    t = __builtin_amdgcn_update_dpp(0, __float_as_int(x), 0x112, 0xf, 0xf, false); // row_shr:2
    x += __int_as_float(t);
    t = __builtin_amdgcn_update_dpp(0, __float_as_int(x), 0x114, 0xf, 0xf, false); // row_shr:4
    x += __int_as_float(t);
    t = __builtin_amdgcn_update_dpp(0, __float_as_int(x), 0x118, 0xf, 0xf, false); // row_shr:8
    x += __int_as_float(t);
    t = __builtin_amdgcn_update_dpp(0, __float_as_int(x), 0x142, 0xa, 0xf, false); // row_bcast:15
    x += __int_as_float(t);
    t = __builtin_amdgcn_update_dpp(0, __float_as_int(x), 0x143, 0xc, 0xf, false); // row_bcast:31
    x += __int_as_float(t);
    return x;
}

__global__ __launch_bounds__(THREADS, 6)   // cap ~85 VGPR -> 3 blocks/CU = 24 waves
void block_attn_res_kernel(
    const float* __restrict__ blocks,   // [7, B*T, D]
    const float* __restrict__ partial,  // [B*T, D]
    const float* __restrict__ qa,
    const float* __restrict__ qm,
    const float* __restrict__ wa,
    const float* __restrict__ wm,
    float* __restrict__ out,            // h_attn [B*T*D] then h_mlp [B*T*D]
    int BT)
{
    const int row = blockIdx.x;
    const int tid = threadIdx.x;
    const int c   = tid * 4;                  // this thread's 4 contiguous cols

    const size_t rowBase = (size_t)row * DDIM;
    const size_t nStride = (size_t)BT * DDIM;

    __shared__ float red[NWAVES * 24];

    // issue ALL V loads first — maximum memory-level parallelism (32 VGPR)
    f32x4 v[NB];
    {
        const float* base = blocks + rowBase + c;
#pragma unroll
        for (int n = 0; n < NB - 1; ++n)
            v[n] = *reinterpret_cast<const f32x4*>(base + (size_t)n * nStride);
        v[NB - 1] = *reinterpret_cast<const f32x4*>(partial + rowBase + c);
    }

    // q*w slices (dead after the stats loop — registers get reused)
    const f32x4 qwa = *reinterpret_cast<const f32x4*>(qa + c) *
                      *reinterpret_cast<const f32x4*>(wa + c);
    const f32x4 qwm = *reinterpret_cast<const f32x4*>(qm + c) *
                      *reinterpret_cast<const f32x4*>(wm + c);

    // per-n stats: wave-reduce and fold straight into LDS (no 24-wide arrays)
    const int wave = tid >> 6;
    const bool is63 = (tid & 63) == 63;
#pragma unroll
    for (int n = 0; n < NB; ++n) {
        float s = 0.f, pa = 0.f, pm = 0.f;
#pragma unroll
        for (int j = 0; j < 4; ++j) {
            s  += v[n][j] * v[n][j];
            pa += qwa[j]  * v[n][j];
            pm += qwm[j]  * v[n][j];
        }
        s  = wave_sum64(s);
        pa = wave_sum64(pa);
        pm = wave_sum64(pm);
        if (is63) {
            red[wave * 24 + n]      = s;
            red[wave * 24 + 8 + n]  = pa;
            red[wave * 24 + 16 + n] = pm;
        }
    }
    __syncthreads();

    // every thread sums the 8 per-wave partial vectors (vector broadcast reads)
    float t24[24];
    {
        const f32x4* r4 = reinterpret_cast<const f32x4*>(red);
#pragma unroll
        for (int g = 0; g < 6; ++g) {
            f32x4 x = r4[g];
#pragma unroll
            for (int w = 1; w < NWAVES; ++w) x += r4[w * 6 + g];
            t24[4 * g + 0] = x.x; t24[4 * g + 1] = x.y;
            t24[4 * g + 2] = x.z; t24[4 * g + 3] = x.w;
        }
    }

    // softmax weights (redundant per thread; small)
    const float inv_sqrt_d = rsqrtf((float)DDIM);
    float lga[NB], lgm[NB];
#pragma unroll
    for (int n = 0; n < NB; ++n) {
        float rms = rsqrtf(t24[n] * (1.0f / DDIM) + 1e-6f);
        lga[n] = t24[8 + n]  * rms * inv_sqrt_d;
        lgm[n] = t24[16 + n] * rms * inv_sqrt_d;
    }
    float ma = lga[0], mm = lgm[0];
#pragma unroll
    for (int n = 1; n < NB; ++n) { ma = fmaxf(ma, lga[n]); mm = fmaxf(mm, lgm[n]); }

    // unnormalized combine, divide by denominators at the end
    f32x4 oa = (f32x4)(0.f), om = (f32x4)(0.f);
    float sa = 0.f, sm = 0.f;
#pragma unroll
    for (int n = 0; n < NB; ++n) {
        float ea = __expf(lga[n] - ma); sa += ea; oa += ea * v[n];
        float em = __expf(lgm[n] - mm); sm += em; om += em * v[n];
    }
    oa *= (1.f / sa);
    om *= (1.f / sm);

    // NT stores (proven +9us): write around L2, keep it for the read stream
    __builtin_nontemporal_store(oa, reinterpret_cast<f32x4*>(out + rowBase + c));
    __builtin_nontemporal_store(om, reinterpret_cast<f32x4*>(out + nStride + rowBase + c));
}

extern "C" void kernel_launch(void* const* d_in, const int* in_sizes, int n_in,
                              void* d_out, int out_size, void* d_ws, size_t ws_size,
                              hipStream_t stream)
{
    const float* blocks  = (const float*)d_in[0];
    const float* partial = (const float*)d_in[1];
    const float* qa      = (const float*)d_in[2];
    const float* qm      = (const float*)d_in[3];
    const float* wa      = (const float*)d_in[4];
    const float* wm      = (const float*)d_in[5];
    float* out = (float*)d_out;

    const int D  = in_sizes[2];          // 2048
    const int BT = in_sizes[1] / D;      // B*T = 8192

    dim3 grid(BT), block(THREADS);
    hipLaunchKernelGGL(block_attn_res_kernel, grid, block, 0, stream,
                       blocks, partial, qa, qm, wa, wm, out, BT);
}

// Round 12
// 122.244 us; speedup vs baseline: 1.0155x; 1.0155x over previous
//
#include <hip/hip_runtime.h>

#define NB 8          // 7 full blocks + 1 partial block
#define DDIM 2048
#define THREADS 256
#define NWAVES (THREADS / 64)

typedef float f32x4 __attribute__((ext_vector_type(4)));

// 64-lane f32 add-reduction via DPP (VALU pipe, no DS ops). Total in lane 63.
__device__ __forceinline__ float wave_sum64(float x) {
    int t;
    t = __builtin_amdgcn_update_dpp(0, __float_as_int(x), 0x111, 0xf, 0xf, false); // row_shr:1
    x += __int_as_float(t);
    t = __builtin_amdgcn_update_dpp(0, __float_as_int(x), 0x112, 0xf, 0xf, false); // row_shr:2
    x += __int_as_float(t);
    t = __builtin_amdgcn_update_dpp(0, __float_as_int(x), 0x114, 0xf, 0xf, false); // row_shr:4
    x += __int_as_float(t);
    t = __builtin_amdgcn_update_dpp(0, __float_as_int(x), 0x118, 0xf, 0xf, false); // row_shr:8
    x += __int_as_float(t);
    t = __builtin_amdgcn_update_dpp(0, __float_as_int(x), 0x142, 0xa, 0xf, false); // row_bcast:15
    x += __int_as_float(t);
    t = __builtin_amdgcn_update_dpp(0, __float_as_int(x), 0x143, 0xc, 0xf, false); // row_bcast:31
    x += __int_as_float(t);
    return x;
}

__global__ __launch_bounds__(THREADS, 4)   // cap at 128 VGPR -> 4 blocks/CU
void block_attn_res_kernel(
    const float* __restrict__ blocks,   // [7, B*T, D]
    const float* __restrict__ partial,  // [B*T, D]
    const float* __restrict__ qa,
    const float* __restrict__ qm,
    const float* __restrict__ wa,
    const float* __restrict__ wm,
    float* __restrict__ out,            // h_attn [B*T*D] then h_mlp [B*T*D]
    int BT)
{
    const int row = blockIdx.x;
    const int tid = threadIdx.x;
    // two fully-coalesced column groups: [4*tid, 4*tid+4) and +D/2
    const int c0 = tid * 4;
    const int c1 = c0 + DDIM / 2;

    const size_t rowBase = (size_t)row * DDIM;
    const size_t nStride = (size_t)BT * DDIM;

    __shared__ float red[NWAVES * 24];
    __shared__ float wgt[16];            // normalized aw[0..7], mw[0..7]

    // issue ALL 16 V loads up front — clean MLP burst (64 VGPR)
    f32x4 v[NB][2];
#pragma unroll
    for (int n = 0; n < NB; ++n) {
        const float* src = (n < NB - 1) ? (blocks + (size_t)n * nStride + rowBase)
                                        : (partial + rowBase);
        v[n][0] = *reinterpret_cast<const f32x4*>(src + c0);
        v[n][1] = *reinterpret_cast<const f32x4*>(src + c1);
    }

    // per-thread q*w slices (dead after stats; registers reused)
    const f32x4 qwa0 = *reinterpret_cast<const f32x4*>(qa + c0) *
                       *reinterpret_cast<const f32x4*>(wa + c0);
    const f32x4 qwa1 = *reinterpret_cast<const f32x4*>(qa + c1) *
                       *reinterpret_cast<const f32x4*>(wa + c1);
    const f32x4 qwm0 = *reinterpret_cast<const f32x4*>(qm + c0) *
                       *reinterpret_cast<const f32x4*>(wm + c0);
    const f32x4 qwm1 = *reinterpret_cast<const f32x4*>(qm + c1) *
                       *reinterpret_cast<const f32x4*>(wm + c1);

    // stats: per n wave-reduce (DPP) and fold straight into LDS
    const int wave = tid >> 6;
    const bool is63 = (tid & 63) == 63;
#pragma unroll
    for (int n = 0; n < NB; ++n) {
        float s = 0.f, pa = 0.f, pm = 0.f;
#pragma unroll
        for (int j = 0; j < 4; ++j) {
            s  += v[n][0][j] * v[n][0][j] + v[n][1][j] * v[n][1][j];
            pa += qwa0[j] * v[n][0][j] + qwa1[j] * v[n][1][j];
            pm += qwm0[j] * v[n][0][j] + qwm1[j] * v[n][1][j];
        }
        s  = wave_sum64(s);
        pa = wave_sum64(pa);
        pm = wave_sum64(pm);
        if (is63) {
            red[wave * 24 + n]      = s;
            red[wave * 24 + 8 + n]  = pa;
            red[wave * 24 + 16 + n] = pm;
        }
    }
    __syncthreads();

    // ONLY wave 0 computes the 16 softmax weights (redundant across its 64
    // lanes — no divergence), lane 0 publishes to LDS. Other 3 waves skip
    // straight to the barrier; redundant tail work per row drops ~4x.
    if (tid < 64) {
        float t24[24];
        {
            const f32x4* r4 = reinterpret_cast<const f32x4*>(red);
#pragma unroll
            for (int g = 0; g < 6; ++g) {
                f32x4 x = r4[g] + r4[6 + g] + r4[12 + g] + r4[18 + g];
                t24[4 * g + 0] = x.x; t24[4 * g + 1] = x.y;
                t24[4 * g + 2] = x.z; t24[4 * g + 3] = x.w;
            }
        }
        const float inv_sqrt_d = rsqrtf((float)DDIM);
        float lga[NB], lgm[NB];
#pragma unroll
        for (int n = 0; n < NB; ++n) {
            float rms = rsqrtf(t24[n] * (1.0f / DDIM) + 1e-6f);
            lga[n] = t24[8 + n]  * rms * inv_sqrt_d;
            lgm[n] = t24[16 + n] * rms * inv_sqrt_d;
        }
        float ma = lga[0], mm = lgm[0];
#pragma unroll
        for (int n = 1; n < NB; ++n) { ma = fmaxf(ma, lga[n]); mm = fmaxf(mm, lgm[n]); }
        float aw[NB], mw[NB];
        float sa = 0.f, sm = 0.f;
#pragma unroll
        for (int n = 0; n < NB; ++n) {
            aw[n] = __expf(lga[n] - ma); sa += aw[n];
            mw[n] = __expf(lgm[n] - mm); sm += mw[n];
        }
        const float ra = 1.f / sa, rm = 1.f / sm;
        if (tid == 0) {
            f32x4* w4 = reinterpret_cast<f32x4*>(wgt);
            w4[0] = (f32x4){aw[0] * ra, aw[1] * ra, aw[2] * ra, aw[3] * ra};
            w4[1] = (f32x4){aw[4] * ra, aw[5] * ra, aw[6] * ra, aw[7] * ra};
            w4[2] = (f32x4){mw[0] * rm, mw[1] * rm, mw[2] * rm, mw[3] * rm};
            w4[3] = (f32x4){mw[4] * rm, mw[5] * rm, mw[6] * rm, mw[7] * rm};
        }
    }
    __syncthreads();

    // all threads: 4 broadcast ds_read_b128 + 32 vec-FMA combine + NT stores
    float awn[NB], mwn[NB];
    {
        const f32x4* w4 = reinterpret_cast<const f32x4*>(wgt);
        f32x4 a0 = w4[0], a1 = w4[1], m0 = w4[2], m1 = w4[3];
        awn[0] = a0.x; awn[1] = a0.y; awn[2] = a0.z; awn[3] = a0.w;
        awn[4] = a1.x; awn[5] = a1.y; awn[6] = a1.z; awn[7] = a1.w;
        mwn[0] = m0.x; mwn[1] = m0.y; mwn[2] = m0.z; mwn[3] = m0.w;
        mwn[4] = m1.x; mwn[5] = m1.y; mwn[6] = m1.z; mwn[7] = m1.w;
    }

    f32x4 oa0 = (f32x4)(0.f), oa1 = (f32x4)(0.f);
    f32x4 om0 = (f32x4)(0.f), om1 = (f32x4)(0.f);
#pragma unroll
    for (int n = 0; n < NB; ++n) {
        oa0 += awn[n] * v[n][0]; oa1 += awn[n] * v[n][1];
        om0 += mwn[n] * v[n][0]; om1 += mwn[n] * v[n][1];
    }

    // NT stores (proven +9us): write around L2, keep it for the read stream
    float* outa = out + rowBase;
    float* outm = out + nStride + rowBase;
    __builtin_nontemporal_store(oa0, reinterpret_cast<f32x4*>(outa + c0));
    __builtin_nontemporal_store(oa1, reinterpret_cast<f32x4*>(outa + c1));
    __builtin_nontemporal_store(om0, reinterpret_cast<f32x4*>(outm + c0));
    __builtin_nontemporal_store(om1, reinterpret_cast<f32x4*>(outm + c1));
}

extern "C" void kernel_launch(void* const* d_in, const int* in_sizes, int n_in,
                              void* d_out, int out_size, void* d_ws, size_t ws_size,
                              hipStream_t stream)
{
    const float* blocks  = (const float*)d_in[0];
    const float* partial = (const float*)d_in[1];
    const float* qa      = (const float*)d_in[2];
    const float* qm      = (const float*)d_in[3];
    const float* wa      = (const float*)d_in[4];
    const float* wm      = (const float*)d_in[5];
    float* out = (float*)d_out;

    const int D  = in_sizes[2];          // 2048
    const int BT = in_sizes[1] / D;      // B*T = 8192

    dim3 grid(BT), block(THREADS);
    hipLaunchKernelGGL(block_attn_res_kernel, grid, block, 0, stream,
                       blocks, partial, qa, qm, wa, wm, out, BT);
}